// Round 1
// 20373.296 us; speedup vs baseline: 1.1499x; 1.1499x over previous
//
#include <hip/hip_runtime.h>

// ---------------------------------------------------------------------------
// LongformerEncoder on MI355X (gfx950).
// B=2 S=4096 D=768 H=12 DH=64 L=12 W=256 FF=3072 HID=384
// Strategy: bf16 MFMA GEMMs (16x16x32), fused banded attention (transposed-
// scores online softmax), persistent multi-WG LSTM with relaxed agent-scope
// (L3 coherence point) h-exchange — no cache invalidates/writebacks in the
// per-step sync protocol.
// ---------------------------------------------------------------------------

typedef short short8 __attribute__((ext_vector_type(8)));
typedef float float4_ __attribute__((ext_vector_type(4)));
typedef unsigned int uint2v __attribute__((ext_vector_type(2)));

#define GLOBAL_AS __attribute__((address_space(1)))
#define LDS_AS __attribute__((address_space(3)))

__device__ __forceinline__ short f2bf(float f) {
  union { float f; unsigned u; } x; x.f = f;
  unsigned r = (x.u + 0x7FFFu + ((x.u >> 16) & 1u)) >> 16;
  return (short)r;
}
__device__ __forceinline__ float sigm(float x) { return 1.0f / (1.0f + __expf(-x)); }
__device__ __forceinline__ float tanh_f(float x) { float e = __expf(2.0f * x); return 1.0f - 2.0f / (e + 1.0f); }

__device__ __forceinline__ void load_lds16(const void* g, void* l) {
  __builtin_amdgcn_global_load_lds((const GLOBAL_AS unsigned int*)g,
                                   (LDS_AS unsigned int*)l, 16, 0, 0);
}

// ---------------------------------------------------------------------------
// Embedding gather + positional add; also key_mask.
__global__ void embed_kernel(const int* __restrict__ x, const float* __restrict__ emb_w,
                             const float* __restrict__ emb_p, float* __restrict__ tmp,
                             float* __restrict__ kmask) {
  int row = blockIdx.x;            // b*4096+s
  int s = row & 4095;
  int tok = x[row];
  const float* ew = emb_w + (size_t)tok * 768;
  const float* ep = emb_p + (size_t)s * 768;
  for (int i = threadIdx.x; i < 768; i += 256)
    tmp[(size_t)row * 768 + i] = ew[i] + ep[i];
  if (threadIdx.x == 0) kmask[row] = (tok != 0) ? 1.0f : 0.0f;
}

// ---------------------------------------------------------------------------
// LayerNorm over D=768: one wave per row. Writes fp32 + bf16.
__global__ __launch_bounds__(256) void ln_kernel(const float* __restrict__ in,
    const float* __restrict__ g, const float* __restrict__ b,
    float* __restrict__ outf, short* __restrict__ outb, int rows) {
  int wave = threadIdx.x >> 6, lane = threadIdx.x & 63;
  int row = blockIdx.x * 4 + wave;
  if (row >= rows) return;
  const float* p = in + (size_t)row * 768;
  float v[12]; float s = 0.f, s2 = 0.f;
#pragma unroll
  for (int j = 0; j < 12; ++j) { v[j] = p[lane + j * 64]; s += v[j]; s2 += v[j] * v[j]; }
#pragma unroll
  for (int k = 1; k < 64; k <<= 1) { s += __shfl_xor(s, k); s2 += __shfl_xor(s2, k); }
  float mean = s * (1.0f / 768.0f);
  float var = s2 * (1.0f / 768.0f) - mean * mean;
  float rstd = rsqrtf(var + 1e-5f);
#pragma unroll
  for (int j = 0; j < 12; ++j) {
    int c = lane + j * 64;
    float o = (v[j] - mean) * rstd * g[c] + b[c];
    outf[(size_t)row * 768 + c] = o;
    outb[(size_t)row * 768 + c] = f2bf(o);
  }
}

// ---------------------------------------------------------------------------
// Per-layer weight prep: fp32 (K,N) -> bf16 (N,K) transposes + QKV bias concat.
__global__ __launch_bounds__(256) void prep_layer_kernel(
    const float* __restrict__ Wq, const float* __restrict__ Wk, const float* __restrict__ Wv,
    const float* __restrict__ Wo, const float* __restrict__ W1, const float* __restrict__ W2,
    const float* __restrict__ bq, const float* __restrict__ bk, const float* __restrict__ bv,
    short* __restrict__ wqkv, short* __restrict__ wo, short* __restrict__ w1,
    short* __restrict__ w2, float* __restrict__ biasqkv, int layer) {
  int bid = blockIdx.x;
  if (bid >= 6912) {  // bias concat: 9 blocks x 256 = 2304
    int i = (bid - 6912) * 256 + threadIdx.x;
    if (i < 2304) {
      float v = (i < 768) ? bq[layer * 768 + i]
               : (i < 1536) ? bk[layer * 768 + i - 768] : bv[layer * 768 + i - 1536];
      biasqkv[i] = v;
    }
    return;
  }
  const float* src; short* dst; int R, C, tr, tc;
  if (bid < 1728) {
    int m = bid / 576; int tloc = bid % 576;
    src = (m == 0 ? Wq : (m == 1 ? Wk : Wv)) + (size_t)layer * 768 * 768;
    dst = wqkv + (size_t)m * 768 * 768; R = 768; C = 768; tr = tloc / 24; tc = tloc % 24;
  } else if (bid < 2304) {
    int tloc = bid - 1728; src = Wo + (size_t)layer * 768 * 768; dst = wo;
    R = 768; C = 768; tr = tloc / 24; tc = tloc % 24;
  } else if (bid < 4608) {
    int tloc = bid - 2304; src = W1 + (size_t)layer * 768 * 3072; dst = w1;
    R = 768; C = 3072; tr = tloc / 96; tc = tloc % 96;
  } else {
    int tloc = bid - 4608; src = W2 + (size_t)layer * 3072 * 768; dst = w2;
    R = 3072; C = 768; tr = tloc / 24; tc = tloc % 24;
  }
  __shared__ float tile[32][33];
  int tx = threadIdx.x & 31, ty = threadIdx.x >> 5;
#pragma unroll
  for (int i = 0; i < 4; ++i)
    tile[ty + i * 8][tx] = src[(size_t)(tr * 32 + ty + i * 8) * C + tc * 32 + tx];
  __syncthreads();
#pragma unroll
  for (int i = 0; i < 4; ++i) {
    int r = ty + i * 8;
    dst[(size_t)(tc * 32 + r) * R + tr * 32 + tx] = f2bf(tile[tx][r]);
  }
}

// ---------------------------------------------------------------------------
// GEMM: C = A(MxK,bf16) * Bt(NxK,bf16)^T + bias, 128x128x64 tiles, 4 waves.
// MODE 0: out bf16 (bias). 1: out bf16 (bias+gelu). 2: out f32 (bias+res).
// MODE 3: out f32 (bias).
template <int MODE>
__global__ __launch_bounds__(256) void gemm_kernel(const short* __restrict__ A,
    const short* __restrict__ Bt, const float* __restrict__ bias,
    const float* __restrict__ res, float* __restrict__ outf, short* __restrict__ outb,
    int M, int N, int K, int ntn) {
  __shared__ short As[128 * 64];
  __shared__ short Bs[128 * 64];
  int tid = threadIdx.x;
  int wave = tid >> 6, lane = tid & 63;
  int l15 = lane & 15, qd = lane >> 4;
  int tm = blockIdx.x / ntn, tn = blockIdx.x % ntn;
  int wm = wave >> 1, wn = wave & 1;
  float4_ acc[4][4] = {};
  for (int k0 = 0; k0 < K; k0 += 64) {
    __syncthreads();
#pragma unroll
    for (int inst = 0; inst < 4; ++inst) {
      int i = inst * 256 + tid;
      const short* ga = A + (size_t)(tm * 128 + (i >> 3)) * K + k0 + (i & 7) * 8;
      const short* gb = Bt + (size_t)(tn * 128 + (i >> 3)) * K + k0 + (i & 7) * 8;
      int ldso = (inst * 256 + wave * 64) * 8;
      load_lds16(ga, &As[ldso]);
      load_lds16(gb, &Bs[ldso]);
    }
    __syncthreads();
#pragma unroll
    for (int ks = 0; ks < 2; ++ks) {
      short8 af[4], bf[4];
#pragma unroll
      for (int mt = 0; mt < 4; ++mt)
        af[mt] = *(const short8*)&As[(wm * 64 + mt * 16 + l15) * 64 + ks * 32 + qd * 8];
#pragma unroll
      for (int nt = 0; nt < 4; ++nt)
        bf[nt] = *(const short8*)&Bs[(wn * 64 + nt * 16 + l15) * 64 + ks * 32 + qd * 8];
#pragma unroll
      for (int mt = 0; mt < 4; ++mt)
#pragma unroll
        for (int nt = 0; nt < 4; ++nt)
          acc[mt][nt] = __builtin_amdgcn_mfma_f32_16x16x32_bf16(af[mt], bf[nt], acc[mt][nt], 0, 0, 0);
    }
  }
  int r0 = tm * 128 + wm * 64, c0 = tn * 128 + wn * 64;
#pragma unroll
  for (int nt = 0; nt < 4; ++nt) {
    int col = c0 + nt * 16 + l15;
    float bv = bias[col];
#pragma unroll
    for (int mt = 0; mt < 4; ++mt) {
      int rowb = r0 + mt * 16 + qd * 4;
#pragma unroll
      for (int r = 0; r < 4; ++r) {
        int row = rowb + r;
        float v = acc[mt][nt][r] + bv;
        if constexpr (MODE == 1) v = v * 0.5f * (1.0f + erff(v * 0.70710678f));
        if constexpr (MODE == 2) v += res[(size_t)row * N + col];
        if constexpr (MODE == 0 || MODE == 1) outb[(size_t)row * N + col] = f2bf(v);
        else outf[(size_t)row * N + col] = v;
      }
    }
  }
}

// ---------------------------------------------------------------------------
// Banded attention. Grid: ((b*12+head)*16+c)*4+qs, block 256 (4 waves x 16 q).
// Transposed scores S^T = K·Q^T so softmax state is per-lane; key-block
// permutation sigma at V^T staging makes P->PV operand repack in-lane.
__global__ __launch_bounds__(256) void attn_kernel(const short* __restrict__ qkv,
    const float* __restrict__ kmask, short* __restrict__ ctx) {
  __shared__ short Ks[256 * 72];
  __shared__ short Vt[64 * 264];
  __shared__ float Ms[256];
  int bid = blockIdx.x;
  int qs = bid & 3; int c = (bid >> 2) & 15; int hh = bid >> 6;
  int head = hh % 12; int bt = hh / 12;
  int tid = threadIdx.x;
  int wave = tid >> 6, lane = tid & 63;
  int l15 = lane & 15, qd = lane >> 4;
  const float SCALE = 0.18033688f;  // 0.125 * log2(e)

  // Q fragments (B-operand of S^T): Q^T[k][q], q = l15, k = qd*8+j (+32*ks)
  short8 qf[2];
  {
    size_t srow = ((size_t)bt * 4096 + c * 256 + qs * 64 + wave * 16 + l15) * 2304;
#pragma unroll
    for (int ks = 0; ks < 2; ++ks)
      qf[ks] = *(const short8*)&qkv[srow + head * 64 + ks * 32 + qd * 8];
  }
  int iq = qs * 64 + wave * 16 + l15;  // query index within 256-chunk

  float m_run = -1e9f, l_run = 0.0f;
  float4_ o4[4] = {};

  for (int kci = 0; kci < 3; ++kci) {
    int kc = c + kci - 1;
    if (kc < 0 || kc > 15) continue;
    __syncthreads();
    {  // stage K (natural), V^T (sigma-permuted columns), mask
      int p = tid;
      size_t kr = ((size_t)bt * 4096 + kc * 256 + p) * 2304;
      int colv = (p & ~31) + (((p >> 2) & 3) << 3) + (((p >> 4) & 1) << 2) + (p & 3);
#pragma unroll
      for (int j8 = 0; j8 < 8; ++j8) {
        short8 kk = *(const short8*)&qkv[kr + 768 + head * 64 + j8 * 8];
        *(short8*)&Ks[p * 72 + j8 * 8] = kk;
        short8 vv = *(const short8*)&qkv[kr + 1536 + head * 64 + j8 * 8];
#pragma unroll
        for (int j = 0; j < 8; ++j) Vt[(j8 * 8 + j) * 264 + colv] = vv[j];
      }
      Ms[p] = kmask[bt * 4096 + kc * 256 + p];
    }
    __syncthreads();

    // S^T tiles: M=keys (16 tiles), N=16 queries, K=dh=64
    float4_ sc[16];
#pragma unroll
    for (int T = 0; T < 16; ++T) {
      float4_ a = {0.f, 0.f, 0.f, 0.f};
#pragma unroll
      for (int ks = 0; ks < 2; ++ks) {
        short8 kf = *(const short8*)&Ks[(T * 16 + l15) * 72 + ks * 32 + qd * 8];
        a = __builtin_amdgcn_mfma_f32_16x16x32_bf16(kf, qf[ks], a, 0, 0, 0);
      }
      sc[T] = a;
    }
    // masking (band + key_mask) in log2 domain, chunk max
    float cm = -1e9f;
#pragma unroll
    for (int T = 0; T < 16; ++T) {
      float4_ mk = *(const float4_*)&Ms[T * 16 + qd * 4];
#pragma unroll
      for (int r = 0; r < 4; ++r) {
        int key = T * 16 + qd * 4 + r;
        bool band = (kci == 1) || (kci == 0 ? (key >= iq) : (key <= iq));
        bool val = band && (mk[r] != 0.0f);
        float sv = val ? sc[T][r] * SCALE : -1e9f;
        sc[T][r] = sv;
        cm = fmaxf(cm, sv);
      }
    }
    cm = fmaxf(cm, __shfl_xor(cm, 16));
    cm = fmaxf(cm, __shfl_xor(cm, 32));
    float mnew = fmaxf(m_run, cm);
    float alpha = exp2f(m_run - mnew);
    m_run = mnew;
    l_run *= alpha;
#pragma unroll
    for (int mt = 0; mt < 4; ++mt) o4[mt] *= alpha;
#pragma unroll
    for (int T = 0; T < 16; ++T)
#pragma unroll
      for (int r = 0; r < 4; ++r) {
        float p = exp2f(sc[T][r] - mnew);
        sc[T][r] = p;
        l_run += p;
      }
    // PV: OUT^T = V^T * P^T; B-frag of P^T is an in-lane repack (sigma-matched)
#pragma unroll
    for (int ks = 0; ks < 8; ++ks) {
      short8 pb;
      pb[0] = f2bf(sc[2 * ks][0]);     pb[1] = f2bf(sc[2 * ks][1]);
      pb[2] = f2bf(sc[2 * ks][2]);     pb[3] = f2bf(sc[2 * ks][3]);
      pb[4] = f2bf(sc[2 * ks + 1][0]); pb[5] = f2bf(sc[2 * ks + 1][1]);
      pb[6] = f2bf(sc[2 * ks + 1][2]); pb[7] = f2bf(sc[2 * ks + 1][3]);
#pragma unroll
      for (int mt = 0; mt < 4; ++mt) {
        short8 va = *(const short8*)&Vt[(mt * 16 + l15) * 264 + ks * 32 + qd * 8];
        o4[mt] = __builtin_amdgcn_mfma_f32_16x16x32_bf16(va, pb, o4[mt], 0, 0, 0);
      }
    }
  }
  l_run += __shfl_xor(l_run, 16);
  l_run += __shfl_xor(l_run, 32);
  float rl = 1.0f / l_run;
  size_t crow = ((size_t)bt * 4096 + c * 256 + qs * 64 + wave * 16 + l15) * 768 + head * 64;
#pragma unroll
  for (int mt = 0; mt < 4; ++mt) {
    unsigned lo = (unsigned short)f2bf(o4[mt][0] * rl) |
                  ((unsigned)(unsigned short)f2bf(o4[mt][1] * rl) << 16);
    unsigned hi = (unsigned short)f2bf(o4[mt][2] * rl) |
                  ((unsigned)(unsigned short)f2bf(o4[mt][3] * rl) << 16);
    uint2v pk; pk[0] = lo; pk[1] = hi;
    *(uint2v*)&ctx[crow + mt * 16 + qd * 4] = pk;
  }
}

// ---------------------------------------------------------------------------
// LSTM prep: Wi fp32->bf16 copy; Wh fp32->bf16 with per-WG gate-grouped rows.
// New Wh layout (NW=4 WGs/dir): dest row' = w*384 + g*96 + dd
//   (WG w owns h-dims [w*96,(w+1)*96), wave g handles gate g)
//   src row = g*384 + w*96 + dd.
__global__ void lstm_prep_kernel(const float* __restrict__ wi_f, const float* __restrict__ wi_b,
    const float* __restrict__ wh_f, const float* __restrict__ wh_b,
    short* __restrict__ wi_bf, short* __restrict__ wh_bf) {
  size_t idx = (size_t)blockIdx.x * 256 + threadIdx.x;
  const size_t NWI = 1179648, NWH = 589824;
  if (idx < 2 * NWI) {
    const float* s = idx < NWI ? wi_f : wi_b;
    size_t k = idx < NWI ? idx : idx - NWI;
    wi_bf[idx] = f2bf(s[k]);
  } else {
    size_t k = idx - 2 * NWI;
    int d = k >= NWH;
    size_t kk = d ? k - NWH : k;
    int row = (int)(kk / 384), col = (int)(kk % 384);
    int w = row / 384, rem = row % 384;
    int g = rem / 96, dd = rem % 96;
    const float* s = d ? wh_b : wh_f;
    wh_bf[k] = f2bf(s[(size_t)(g * 384 + w * 96 + dd) * 384 + col]);
  }
}

__global__ void lstm_init_kernel(short* __restrict__ hbuf, unsigned* __restrict__ cnt) {
  int idx = blockIdx.x * 256 + threadIdx.x;
  if (idx < 24576) hbuf[idx] = 0;
  if (idx < 64) cnt[idx] = 0;
}

// ---------------------------------------------------------------------------
// Persistent LSTM: 8 WGs (4 per direction). WG w owns h-dims [w*96,w*96+96)
// for all 4 gates (384 Wh rows; wave g holds gate g's 96x384 A-frags resident,
// 288 VGPRs). Cross-WG h exchange entirely via relaxed agent-scope (sc1, L3
// coherence point) atomics: producer {h stores -> vmcnt(0) -> counter add},
// consumer {relaxed poll -> agent loads}. No buffer_inv / buffer_wbl2 per
// step. G (Wi*x) reads software-pipelined one step ahead in registers.
__global__ __launch_bounds__(256, 1) void lstm_kernel(const short* __restrict__ Whb,
    const float* __restrict__ G, short* __restrict__ hbuf, unsigned* __restrict__ cnt,
    float* __restrict__ out) {
  int wg = blockIdx.x; int dir = wg >> 2; int w = wg & 3;
  int tid = threadIdx.x; int wave = tid >> 6; int lane = tid & 63;
  int l15 = lane & 15, qd = lane >> 4;
  __shared__ float gbuf[4][2][96];

  // A-frags: wave g owns rows [dir*1536 + w*384 + g*96, +96) of permuted Wh.
  short8 afrag[6][12];
#pragma unroll
  for (int tt = 0; tt < 6; ++tt)
#pragma unroll
    for (int ks = 0; ks < 12; ++ks)
      afrag[tt][ks] = *(const short8*)&Whb[
          ((size_t)dir * 1536 + w * 384 + wave * 96 + tt * 16 + l15) * 384 + ks * 32 + qd * 8];

  unsigned* mycnt = cnt + dir * 16;
  // wave0 activation ownership: 3 (bb,j) pairs per lane, p = lane + 64*k.
  int pj[3], pb[3];
#pragma unroll
  for (int k = 0; k < 3; ++k) { int p = lane + 64 * k; pb[k] = (p >= 96) ? 1 : 0; pj[k] = p - pb[k] * 96; }
  float cst[3] = {0.f, 0.f, 0.f};
  float ginC[3][4], ginN[3][4];
  if (wave == 0) {  // prologue: gin for t0 straight into ginC
    int t0 = dir ? 4095 : 0;
#pragma unroll
    for (int k = 0; k < 3; ++k) {
      const float* Gp = G + ((size_t)dir * 8192 + pb[k] * 4096 + t0) * 1536 + w * 96 + pj[k];
#pragma unroll
      for (int g = 0; g < 4; ++g) ginC[k][g] = Gp[g * 384];
    }
  }

  for (int s = 0; s < 4096; ++s) {
    int t = dir ? (4095 - s) : s;
    // ---- sync-in: wait until all 4 WGs of this direction produced h_s ----
    if (s > 0) {
      if (lane == 0) {
        unsigned tgt = 4u * (unsigned)s;
        while (__hip_atomic_load(mycnt, __ATOMIC_RELAXED, __HIP_MEMORY_SCOPE_AGENT) < tgt)
          __builtin_amdgcn_s_sleep(1);
      }
      asm volatile("" ::: "memory");  // keep h loads after the poll
    }
    // ---- read h_s (only batch rows bb<2 are real) via agent-scope loads ----
    const short* hb = hbuf + (size_t)(dir * 2 + (s & 1)) * 2 * 384;
    short8 bfrag[12] = {};
    if (l15 < 2) {
      const unsigned long long* hp = (const unsigned long long*)(hb + l15 * 384 + qd * 8);
#pragma unroll
      for (int ks = 0; ks < 12; ++ks) {
        union { unsigned long long q[2]; short8 v; } u;
        u.q[0] = __hip_atomic_load(hp + ks * 8, __ATOMIC_RELAXED, __HIP_MEMORY_SCOPE_AGENT);
        u.q[1] = __hip_atomic_load(hp + ks * 8 + 1, __ATOMIC_RELAXED, __HIP_MEMORY_SCOPE_AGENT);
        bfrag[ks] = u.v;
      }
    }
    // ---- recurrent GEMM: wave g -> gate g preactivations for 96 dims ----
    float4_ acc[6] = {};
#pragma unroll
    for (int ks = 0; ks < 12; ++ks)
#pragma unroll
      for (int tt = 0; tt < 6; ++tt)
        acc[tt] = __builtin_amdgcn_mfma_f32_16x16x32_bf16(afrag[tt][ks], bfrag[ks], acc[tt], 0, 0, 0);
    if (l15 < 2) {
#pragma unroll
      for (int tt = 0; tt < 6; ++tt)
        *(float4_*)&gbuf[wave][l15][tt * 16 + qd * 4] = acc[tt];
    }
    __syncthreads();
    // ---- wave0: activations, h store (agent scope), flag, gin prefetch ----
    if (wave == 0) {
      if (s > 0) {  // rotate prefetched gin (issued one step ago; arrived)
#pragma unroll
        for (int k = 0; k < 3; ++k)
#pragma unroll
          for (int g = 0; g < 4; ++g) ginC[k][g] = ginN[k][g];
      }
      short* hn = hbuf + (size_t)(dir * 2 + ((s + 1) & 1)) * 2 * 384;
#pragma unroll
      for (int k = 0; k < 3; ++k) {
        int j = pj[k], bb = pb[k];
        float gi = gbuf[0][bb][j] + ginC[k][0];
        float gf = gbuf[1][bb][j] + ginC[k][1];
        float gg = gbuf[2][bb][j] + ginC[k][2];
        float go = gbuf[3][bb][j] + ginC[k][3];
        float cc = sigm(gf) * cst[k] + sigm(gi) * tanh_f(gg);
        cst[k] = cc;
        float hh2 = sigm(go) * tanh_f(cc);
        __hip_atomic_store(&hn[bb * 384 + w * 96 + j], f2bf(hh2),
                           __ATOMIC_RELAXED, __HIP_MEMORY_SCOPE_AGENT);
        if ((t & 63) == 0)
          out[((size_t)bb * 64 + (t >> 6)) * 768 + dir * 384 + w * 96 + j] = hh2;
      }
      asm volatile("s_waitcnt vmcnt(0)" ::: "memory");  // h stores at L3 before flag
      if (lane == 0)
        __hip_atomic_fetch_add(mycnt, 1u, __ATOMIC_RELAXED, __HIP_MEMORY_SCOPE_AGENT);
      if (s + 1 < 4096) {  // issue next-step gin loads; consumed next iteration
        int t2 = dir ? (4095 - (s + 1)) : (s + 1);
#pragma unroll
        for (int k = 0; k < 3; ++k) {
          const float* Gp = G + ((size_t)dir * 8192 + pb[k] * 4096 + t2) * 1536 + w * 96 + pj[k];
#pragma unroll
          for (int g = 0; g < 4; ++g) ginN[k][g] = Gp[g * 384];
        }
      }
    }
  }
}

// ---------------------------------------------------------------------------
extern "C" void kernel_launch(void* const* d_in, const int* in_sizes, int n_in,
                              void* d_out, int out_size, void* d_ws, size_t ws_size,
                              hipStream_t stream) {
  const int*   x     = (const int*)d_in[0];
  const float* emb_w = (const float*)d_in[1];
  const float* emb_p = (const float*)d_in[2];
  const float* ln_eg = (const float*)d_in[3];
  const float* ln_eb = (const float*)d_in[4];
  const float* Wq    = (const float*)d_in[5];
  const float* bq    = (const float*)d_in[6];
  const float* Wk    = (const float*)d_in[7];
  const float* bk    = (const float*)d_in[8];
  const float* Wv    = (const float*)d_in[9];
  const float* bv    = (const float*)d_in[10];
  const float* Wo    = (const float*)d_in[11];
  const float* bo    = (const float*)d_in[12];
  const float* ln1g  = (const float*)d_in[13];
  const float* ln1b  = (const float*)d_in[14];
  const float* W1    = (const float*)d_in[15];
  const float* bf1   = (const float*)d_in[16];
  const float* W2    = (const float*)d_in[17];
  const float* bf2   = (const float*)d_in[18];
  const float* ln2g  = (const float*)d_in[19];
  const float* ln2b  = (const float*)d_in[20];
  const float* wi_f  = (const float*)d_in[21];
  const float* wh_f  = (const float*)d_in[22];
  const float* b_f   = (const float*)d_in[23];
  const float* wi_b  = (const float*)d_in[24];
  const float* wh_b  = (const float*)d_in[25];
  const float* b_b   = (const float*)d_in[26];

  char* ws = (char*)d_ws;
  size_t off = 0;
  auto alloc = [&](size_t n) { size_t o = off; off += (n + 255) & ~(size_t)255; return o; };
  float* h_f32    = (float*)(ws + alloc(8192ull * 768 * 4));
  short* h_b16    = (short*)(ws + alloc(8192ull * 768 * 2));
  size_t alias0   = alloc(125829120ull);
  short* qkv      = (short*)(ws + alias0);
  short* ctx      = (short*)(ws + alias0 + 37748736ull);
  float* tmp      = (float*)(ws + alias0 + 50331648ull);
  short* ffn1     = (short*)(ws + alias0 + 75497472ull);
  float* G        = (float*)(ws + alias0);  // aliases encoder scratch (dead by then)
  short* wqkv_t   = (short*)(ws + alloc(2304ull * 768 * 2));
  short* wo_t     = (short*)(ws + alloc(768ull * 768 * 2));
  short* w1_t     = (short*)(ws + alloc(3072ull * 768 * 2));
  short* w2_t     = (short*)(ws + alloc(768ull * 3072 * 2));
  float* biasqkv  = (float*)(ws + alloc(2304 * 4));
  short* wi_bf    = (short*)(ws + alloc(2ull * 1536 * 768 * 2));
  short* wh_bf    = (short*)(ws + alloc(2ull * 1536 * 384 * 2));
  short* hbuf     = (short*)(ws + alloc(2ull * 2 * 16 * 384 * 2));
  unsigned* cnt   = (unsigned*)(ws + alloc(256));
  float* kmask    = (float*)(ws + alloc(8192 * 4));
  if (ws_size < off) return;  // workspace too small; output stays poisoned (visible failure)

  embed_kernel<<<8192, 256, 0, stream>>>(x, emb_w, emb_p, tmp, kmask);
  ln_kernel<<<2048, 256, 0, stream>>>(tmp, ln_eg, ln_eb, h_f32, h_b16, 8192);

  for (int l = 0; l < 12; ++l) {
    prep_layer_kernel<<<6921, 256, 0, stream>>>(Wq, Wk, Wv, Wo, W1, W2, bq, bk, bv,
                                                wqkv_t, wo_t, w1_t, w2_t, biasqkv, l);
    gemm_kernel<0><<<64 * 18, 256, 0, stream>>>(h_b16, wqkv_t, biasqkv, nullptr,
                                                nullptr, qkv, 8192, 2304, 768, 18);
    attn_kernel<<<1536, 256, 0, stream>>>(qkv, kmask, ctx);
    gemm_kernel<2><<<64 * 6, 256, 0, stream>>>(ctx, wo_t, bo + l * 768, h_f32,
                                               tmp, nullptr, 8192, 768, 768, 6);
    ln_kernel<<<2048, 256, 0, stream>>>(tmp, ln1g + l * 768, ln1b + l * 768, h_f32, h_b16, 8192);
    gemm_kernel<1><<<64 * 24, 256, 0, stream>>>(h_b16, w1_t, bf1 + l * 3072, nullptr,
                                                nullptr, ffn1, 8192, 3072, 768, 24);
    gemm_kernel<2><<<64 * 6, 256, 0, stream>>>(ffn1, w2_t, bf2 + l * 768, h_f32,
                                               tmp, nullptr, 8192, 768, 3072, 6);
    ln_kernel<<<2048, 256, 0, stream>>>(tmp, ln2g + l * 768, ln2b + l * 768, h_f32, h_b16, 8192);
  }

  lstm_prep_kernel<<<13824, 256, 0, stream>>>(wi_f, wi_b, wh_f, wh_b, wi_bf, wh_bf);
  gemm_kernel<3><<<64 * 12, 256, 0, stream>>>(h_b16, wi_bf, b_f, nullptr,
                                              G, nullptr, 8192, 1536, 768, 12);
  gemm_kernel<3><<<64 * 12, 256, 0, stream>>>(h_b16, wi_bf + 1536ull * 768, b_b, nullptr,
                                              G + 8192ull * 1536, nullptr, 8192, 1536, 768, 12);
  lstm_init_kernel<<<96, 256, 0, stream>>>(hbuf, cnt);
  lstm_kernel<<<8, 256, 0, stream>>>(wh_bf, G, hbuf, cnt, (float*)d_out);
}